// Round 2
// baseline (902.550 us; speedup 1.0000x reference)
//
#include <hip/hip_runtime.h>

typedef unsigned short u16;
typedef unsigned int u32;
typedef __attribute__((ext_vector_type(8))) short short8;   // 8 x bf16 (4 VGPRs)
typedef __attribute__((ext_vector_type(4))) float f32x4;

#define GLOAD_LDS16(gp, lp) __builtin_amdgcn_global_load_lds( \
    (const __attribute__((address_space(1))) void*)(gp), \
    (__attribute__((address_space(3))) void*)(lp), 16, 0, 0)

#define LOG2E 1.4426950408889634f

__device__ __forceinline__ u16 f2bf(float f){
  u32 u = __builtin_bit_cast(u32, f);
  u = (u + 0x7fffu + ((u >> 16) & 1u)) >> 16;   // RNE
  return (u16)u;
}

// ---------------- x fp32 -> bf16 ----------------
__global__ __launch_bounds__(256) void convx_kernel(const float* __restrict__ x,
                                                    u16* __restrict__ xb){
  int i = blockIdx.x*256 + threadIdx.x;          // 524288 threads, 8 elems each
  const float4* p = (const float4*)x;
  float4 a = p[2*i], b = p[2*i+1];
  short8 r;
  r[0]=(short)f2bf(a.x); r[1]=(short)f2bf(a.y); r[2]=(short)f2bf(a.z); r[3]=(short)f2bf(a.w);
  r[4]=(short)f2bf(b.x); r[5]=(short)f2bf(b.y); r[6]=(short)f2bf(b.z); r[7]=(short)f2bf(b.w);
  ((short8*)xb)[i] = r;
}

// ------------- weight fp32 [K][ncols] -> bf16 W^T [row_off+col][1024] -------------
__global__ __launch_bounds__(256) void convw_kernel(const float* __restrict__ src, int ncols,
                                                    u16* __restrict__ dst, int row_off){
  __shared__ __attribute__((aligned(16))) u16 tile[64*72];
  int c0 = blockIdx.x*64, k0 = blockIdx.y*64;
  int t = threadIdx.x;
  int col = t & 63, kk = t >> 6;
  #pragma unroll
  for (int i=0;i<16;i++){
    int k = i*4 + kk;
    tile[col*72 + k] = f2bf(src[(size_t)(k0+k)*ncols + c0 + col]);  // coalesced read
  }
  __syncthreads();
  int kcol = t & 63, cr = t >> 6;
  #pragma unroll
  for (int i=0;i<16;i++){
    int colr = i*4 + cr;
    dst[(size_t)(row_off + c0 + colr)*1024 + k0 + kcol] = tile[colr*72 + kcol]; // coalesced write
  }
}

// ---------------- 128x128x(K) bf16 GEMM core (A[M][K], Bt[N][K]) ----------------
// LDS tiles [128 rows][64 k] bf16, linear, with XOR swizzle applied on the GLOBAL
// source (G21: both-sides-or-neither) so ds_read_b128 fragment reads are conflict-free
// (each 8-lane phase covers all 8 16B slots of a bank-group).
__device__ __forceinline__ void gemm128_core(const u16* __restrict__ A, const u16* __restrict__ Bt,
    int lda, int ldb, int row0, int col0, int K, u16* As, u16* Bs, f32x4 acc[4][4]){
  int t = threadIdx.x, w = t>>6, lane = t&63, lr = lane&15, lg = lane>>4;
  int wr = w>>1, wc = w&1;
  #pragma unroll
  for (int m=0;m<4;m++)
    #pragma unroll
    for (int n=0;n<4;n++) acc[m][n] = (f32x4){0.f,0.f,0.f,0.f};
  for (int kt=0; kt<K; kt+=64){
    #pragma unroll
    for (int i=0;i<4;i++){
      int p = w*256 + i*64 + lane;            // 1024 slots x 16B per tile
      int row = p>>3, g = p&7;
      int koff = kt + ((g ^ (row&7))<<3);     // pre-swizzled global source
      GLOAD_LDS16(A  + (size_t)(row0+row)*lda + koff, As + p*8);
      GLOAD_LDS16(Bt + (size_t)(col0+row)*ldb + koff, Bs + p*8);
    }
    __syncthreads();
    #pragma unroll
    for (int ks=0; ks<2; ++ks){
      short8 af[4], bf[4];
      #pragma unroll
      for (int m=0;m<4;m++){
        int row = wr*64 + m*16 + lr;
        af[m] = *(const short8*)(As + row*64 + (((ks*4+lg) ^ (row&7))<<3));
      }
      #pragma unroll
      for (int n=0;n<4;n++){
        int row = wc*64 + n*16 + lr;
        bf[n] = *(const short8*)(Bs + row*64 + (((ks*4+lg) ^ (row&7))<<3));
      }
      #pragma unroll
      for (int m=0;m<4;m++)
        #pragma unroll
        for (int n=0;n<4;n++)
          acc[m][n] = __builtin_amdgcn_mfma_f32_16x16x32_bf16(af[m], bf[n], acc[m][n], 0, 0, 0);
    }
    __syncthreads();
  }
}

// ---------------- GEMM1: xb @ Wqkv -> Q (scaled, [B,H,N,D]), K [B,H,N,D], V^T [B,H,D,N] ----------------
__global__ __launch_bounds__(256) void gemm_qkv_kernel(const u16* __restrict__ xb, const u16* __restrict__ Wt,
    const float* __restrict__ bq, const float* __restrict__ bkv,
    u16* __restrict__ Q, u16* __restrict__ Kb, u16* __restrict__ Vt){
  __shared__ __attribute__((aligned(16))) u16 As[128*64];
  __shared__ __attribute__((aligned(16))) u16 Bs[128*64];
  f32x4 acc[4][4];
  int row0 = blockIdx.y*128, col0 = blockIdx.x*128;
  gemm128_core(xb, Wt, 1024, 1024, row0, col0, 1024, As, Bs, acc);
  int t = threadIdx.x, w = t>>6, lane = t&63, lr = lane&15, lg = lane>>4;
  int wr = w>>1, wc = w&1;
  #pragma unroll
  for (int m=0;m<4;m++)
    #pragma unroll
    for (int n=0;n<4;n++)
      #pragma unroll
      for (int r=0;r<4;r++){
        int grow = row0 + wr*64 + m*16 + lg*4 + r;   // token index
        int gcol = col0 + wc*64 + n*16 + lr;         // qkv col
        float v = acc[m][n][r];
        int b = grow>>11, nt = grow&2047;
        if (gcol < 1024){
          int h = gcol>>6, d = gcol&63;
          Q[(((size_t)b*16 + h)*2048 + nt)*64 + d] = f2bf((v + bq[gcol]) * 0.125f);
        } else if (gcol < 2048){
          int c2 = gcol - 1024; int h = c2>>6, d = c2&63;
          Kb[(((size_t)b*16 + h)*2048 + nt)*64 + d] = f2bf(v + bkv[c2]);
        } else {
          int c2 = gcol - 1024; int cv = gcol - 2048; int h = cv>>6, d = cv&63;
          Vt[(((size_t)b*16 + h)*64 + d)*2048 + nt] = f2bf(v + bkv[c2]);
        }
      }
}

// ---------------- GEMM2: AO @ Wo + bo -> out fp32 ----------------
__global__ __launch_bounds__(256) void gemm_out_kernel(const u16* __restrict__ AO, const u16* __restrict__ Wt,
    const float* __restrict__ bo, float* __restrict__ out){
  __shared__ __attribute__((aligned(16))) u16 As[128*64];
  __shared__ __attribute__((aligned(16))) u16 Bs[128*64];
  f32x4 acc[4][4];
  int row0 = blockIdx.y*128, col0 = blockIdx.x*128;
  gemm128_core(AO, Wt, 1024, 1024, row0, col0, 1024, As, Bs, acc);
  int t = threadIdx.x, w = t>>6, lane = t&63, lr = lane&15, lg = lane>>4;
  int wr = w>>1, wc = w&1;
  #pragma unroll
  for (int m=0;m<4;m++)
    #pragma unroll
    for (int n=0;n<4;n++)
      #pragma unroll
      for (int r=0;r<4;r++){
        int grow = row0 + wr*64 + m*16 + lg*4 + r;
        int gcol = col0 + wc*64 + n*16 + lr;
        out[(size_t)grow*1024 + gcol] = acc[m][n][r] + bo[gcol];
      }
}

// ---------------- flash attention: S = Q K^T + bias, online softmax, O = P V ----------------
// 1D grid of 1024 blocks, XCD-aware decode: XCD i (= blockIdx%8, round-robin per m09)
// owns bh in {i, i+8, i+16, i+24} -> 2MB K/V resident per 4MB L2. All 1024 blocks
// co-resident (24KB LDS -> >=4 blocks/CU), so the partition holds kernel-wide.
// 4 waves x 16 q-rows; KV tile 64.
__global__ __launch_bounds__(256) void attn_kernel(const u16* __restrict__ Q, const u16* __restrict__ Kb,
    const u16* __restrict__ Vt, const float* __restrict__ bias, u16* __restrict__ AO){
  __shared__ __attribute__((aligned(16))) u16 Ks[64*64];
  __shared__ __attribute__((aligned(16))) u16 Vs[64*64];       // V^T tile: [d][kv]
  __shared__ __attribute__((aligned(16))) u16 Ps[4][16*64];    // per-wave P tile
  int id = blockIdx.x;
  int bh = (id & 7) + 8*((id >> 3) & 3);       // XCD-aware: bh%8 == XCD id
  int q0 = (id >> 5) << 6;                     // 32 q-tiles of 64 rows
  int b = bh>>4, h = bh&15;
  int t = threadIdx.x, w = t>>6, lane = t&63, lr = lane&15, lg = lane>>4;
  short8 qf[2];
  {
    int qrow = q0 + w*16 + lr;
    const u16* qp = Q + ((size_t)bh*2048 + qrow)*64;
    qf[0] = *(const short8*)(qp + lg*8);
    qf[1] = *(const short8*)(qp + 32 + lg*8);
  }
  float m_r[4] = {-INFINITY,-INFINITY,-INFINITY,-INFINITY};
  float l_r[4] = {0.f,0.f,0.f,0.f};
  f32x4 o[4];
  #pragma unroll
  for (int db=0; db<4; ++db) o[db] = (f32x4){0.f,0.f,0.f,0.f};
  const size_t bias_row0 = (size_t)bh*2048;

  for (int kv0=0; kv0<2048; kv0+=64){
    // stage K tile [kv][d] and V^T tile [d][kv], swizzled-source + linear LDS
    #pragma unroll
    for (int i=0;i<2;i++){
      int p = w*128 + i*64 + lane;
      int row = p>>3, g = p&7;
      GLOAD_LDS16(Kb + ((size_t)bh*2048 + kv0 + row)*64 + ((g ^ (row&7))<<3), Ks + p*8);
      GLOAD_LDS16(Vt + ((size_t)bh*64 + row)*2048 + kv0 + ((g ^ (row&7))<<3), Vs + p*8);
    }
    // bias prefetch into registers (the 536MB one-shot stream) — nontemporal so it
    // doesn't evict the L2-resident K/V; overlaps the LDS staging above.
    float bv[4][4];
    #pragma unroll
    for (int r=0;r<4;r++){
      int qrow = q0 + w*16 + lg*4 + r;
      const float* bp = bias + (bias_row0 + qrow)*2048 + kv0 + lr;
      #pragma unroll
      for (int cb=0;cb<4;cb++) bv[r][cb] = __builtin_nontemporal_load(bp + cb*16);
    }
    __syncthreads();
    // S = Q K^T (scale folded into Q at projection time)
    f32x4 s[4];
    #pragma unroll
    for (int cb=0;cb<4;cb++) s[cb] = (f32x4){0.f,0.f,0.f,0.f};
    #pragma unroll
    for (int ks=0; ks<2; ++ks){
      short8 kf[4];
      #pragma unroll
      for (int cb=0;cb<4;cb++){
        int kv = cb*16 + lr;
        kf[cb] = *(const short8*)(Ks + kv*64 + (((ks*4+lg) ^ (kv&7))<<3));
      }
      #pragma unroll
      for (int cb=0;cb<4;cb++)
        s[cb] = __builtin_amdgcn_mfma_f32_16x16x32_bf16(qf[ks], kf[cb], s[cb], 0,0,0);
    }
    // online softmax (rows live on 16-lane groups; reduce via shfl_xor 1..8)
    float pm[4][4]; float alpha[4];
    #pragma unroll
    for (int r=0;r<4;r++){
      float sv[4]; float mx = -INFINITY;
      #pragma unroll
      for (int cb=0;cb<4;cb++){ sv[cb] = s[cb][r] + bv[r][cb]; mx = fmaxf(mx, sv[cb]); }
      #pragma unroll
      for (int d=1; d<16; d<<=1) mx = fmaxf(mx, __shfl_xor(mx, d));
      float mn = fmaxf(m_r[r], mx);
      float al = exp2f((m_r[r]-mn)*LOG2E);
      float rs = 0.f;
      #pragma unroll
      for (int cb=0;cb<4;cb++){ float pv = exp2f((sv[cb]-mn)*LOG2E); pm[r][cb] = pv; rs += pv; }
      #pragma unroll
      for (int d=1; d<16; d<<=1) rs += __shfl_xor(rs, d);
      l_r[r] = l_r[r]*al + rs;
      m_r[r] = mn; alpha[r] = al;
    }
    #pragma unroll
    for (int db=0; db<4; ++db){
      f32x4 ov = o[db];
      ov[0]*=alpha[0]; ov[1]*=alpha[1]; ov[2]*=alpha[2]; ov[3]*=alpha[3];
      o[db] = ov;
    }
    // P -> per-wave LDS (bf16), XOR-swizzled for conflict-free b128 A-frag reads
    #pragma unroll
    for (int r=0;r<4;r++){
      int rw = lg*4 + r;
      #pragma unroll
      for (int cb=0;cb<4;cb++){
        int col = cb*16 + lr;
        Ps[w][rw*64 + (((col>>3) ^ (rw&7))<<3) + (col&7)] = f2bf(pm[r][cb]);
      }
    }
    __syncthreads();   // orders Ps cross-lane write->read; Ks/Vs still live until next barrier
    // O += P V
    #pragma unroll
    for (int ks=0; ks<2; ++ks){
      short8 pf = *(const short8*)(Ps[w] + lr*64 + (((ks*4+lg) ^ (lr&7))<<3));
      #pragma unroll
      for (int db=0; db<4; ++db){
        int d = db*16 + lr;
        short8 vf = *(const short8*)(Vs + d*64 + (((ks*4+lg) ^ (d&7))<<3));
        o[db] = __builtin_amdgcn_mfma_f32_16x16x32_bf16(pf, vf, o[db], 0,0,0);
      }
    }
    __syncthreads();   // protect Ks/Vs before next stage
  }
  // normalize + write AO [B][N][H*D] bf16
  #pragma unroll
  for (int db=0; db<4; ++db)
    #pragma unroll
    for (int r=0;r<4;r++){
      int qrow = q0 + w*16 + lg*4 + r;
      AO[((size_t)b*2048 + qrow)*1024 + h*64 + db*16 + lr] = f2bf(o[db][r] / l_r[r]);
    }
}

// ---------------- launch ----------------
extern "C" void kernel_launch(void* const* d_in, const int* in_sizes, int n_in,
                              void* d_out, int out_size, void* d_ws, size_t ws_size,
                              hipStream_t stream) {
  const float* x    = (const float*)d_in[0];
  const float* bias = (const float*)d_in[1];
  const float* Wq   = (const float*)d_in[2];
  const float* bq   = (const float*)d_in[3];
  const float* Wkv  = (const float*)d_in[4];
  const float* bkv  = (const float*)d_in[5];
  const float* Wo   = (const float*)d_in[6];
  const float* bo   = (const float*)d_in[7];
  float* out = (float*)d_out;
  char* ws = (char*)d_ws;
  // workspace layout (40 MB total; AO aliases xb — xb is dead after gemm_qkv)
  u16* xb    = (u16*)(ws);                       //  8 MB  [4096][1024]
  u16* WqkvT = (u16*)(ws + 8388608);             //  6 MB  [3072][1024]
  u16* WoT   = (u16*)(ws + 14680064);            //  2 MB  [1024][1024]
  u16* Q     = (u16*)(ws + 16777216);            //  8 MB  [B,H,N,D] (scaled)
  u16* Kb    = (u16*)(ws + 25165824);            //  8 MB  [B,H,N,D]
  u16* Vt    = (u16*)(ws + 33554432);            //  8 MB  [B,H,D,N]
  u16* AO    = xb;                               //  aliases xb

  convx_kernel<<<2048, 256, 0, stream>>>(x, xb);
  convw_kernel<<<dim3(16,16), 256, 0, stream>>>(Wq,  1024, WqkvT, 0);
  convw_kernel<<<dim3(32,16), 256, 0, stream>>>(Wkv, 2048, WqkvT, 1024);
  convw_kernel<<<dim3(16,16), 256, 0, stream>>>(Wo,  1024, WoT, 0);
  gemm_qkv_kernel<<<dim3(24,32), 256, 0, stream>>>(xb, WqkvT, bq, bkv, Q, Kb, Vt);
  attn_kernel<<<1024, 256, 0, stream>>>(Q, Kb, Vt, bias, AO);
  gemm_out_kernel<<<dim3(8,32), 256, 0, stream>>>(AO, WoT, bo, out);
}